// Round 2
// baseline (426.403 us; speedup 1.0000x reference)
//
#include <hip/hip_runtime.h>
#include <math.h>

#define BATCH 16
#define SEQL  256
#define HDIM  64
#define NHEAD 2
#define HSZ   32
#define NBLK  2
#define PADID 49999
#define NEGV  -4294967295.0f
#define LNEPS 1e-8f
#define INV_SQRT_HS 0.17677669529663687f

__device__ __forceinline__ float waveReduceSum(float v) {
#pragma unroll
    for (int o = 32; o > 0; o >>= 1) v += __shfl_xor(v, o);
    return v;
}

// One wave (64 threads) per row: LN1, then Q/Kp/Vp projections with bias +
// abs-pos embedding folding.  Kp = K + aK, Vp = V + aV.
__global__ __launch_bounds__(64) void prep_proj_kernel(
    const float* __restrict__ xin, const int* __restrict__ seqs_data,
    const int* __restrict__ positions,
    const float* __restrict__ Qw, const float* __restrict__ Qb,
    const float* __restrict__ Kw, const float* __restrict__ Kb,
    const float* __restrict__ Vw, const float* __restrict__ Vb,
    const float* __restrict__ g1, const float* __restrict__ b1,
    const float* __restrict__ apK, const float* __restrict__ apV,
    float* __restrict__ q_in, float* __restrict__ Qo,
    float* __restrict__ Kp, float* __restrict__ Vp,
    int apply_keep)
{
    const int row = blockIdx.x;
    const int t = threadIdx.x;
    float x = xin[(size_t)row * HDIM + t];
    if (apply_keep && seqs_data[row] == PADID) x = 0.f;

    float mean = waveReduceSum(x) * (1.f / HDIM);
    float d = x - mean;
    float var = waveReduceSum(d * d) * (1.f / HDIM);
    float q = g1[t] * d / sqrtf(var + LNEPS) + b1[t];

    __shared__ float xs[HDIM];
    __shared__ float qs[HDIM];
    xs[t] = x; qs[t] = q;
    q_in[(size_t)row * HDIM + t] = q;
    __syncthreads();

    int pos = positions[row];
    float aK = (pos != 0) ? apK[(size_t)pos * HDIM + t] : 0.f;
    float aV = (pos != 0) ? apV[(size_t)pos * HDIM + t] : 0.f;

    const float4* qw4 = (const float4*)(Qw + (size_t)t * HDIM);
    const float4* kw4 = (const float4*)(Kw + (size_t)t * HDIM);
    const float4* vw4 = (const float4*)(Vw + (size_t)t * HDIM);
    float aq = 0.f, ak = 0.f, av = 0.f;
#pragma unroll
    for (int j = 0; j < 16; ++j) {
        float4 wq = qw4[j], wk = kw4[j], wv = vw4[j];
        float q0 = qs[4*j+0], q1 = qs[4*j+1], q2 = qs[4*j+2], q3 = qs[4*j+3];
        float y0 = xs[4*j+0], y1 = xs[4*j+1], y2 = xs[4*j+2], y3 = xs[4*j+3];
        aq += q0*wq.x + q1*wq.y + q2*wq.z + q3*wq.w;
        ak += y0*wk.x + y1*wk.y + y2*wk.z + y3*wk.w;
        av += y0*wv.x + y1*wv.y + y2*wv.z + y3*wv.w;
    }
    Qo[(size_t)row * HDIM + t] = aq + Qb[t];
    Kp[(size_t)row * HDIM + t] = ak + Kb[t] + aK;
    Vp[(size_t)row * HDIM + t] = av + Vb[t] + aV;
}

// One 256-thread block per (b, l) query row.  Phase 1: thread-per-m scores for
// both heads (Q via LDS broadcast).  Phase 2: block softmax.  Phase 3: threads
// re-mapped to (chunk, hd) for the output reduction; tV gather index is
// wave-uniform per iteration (broadcast row read).
__global__ __launch_bounds__(256) void attn_kernel(
    const float* __restrict__ Qo, const float* __restrict__ Kp,
    const float* __restrict__ Vp, const float* __restrict__ q_in,
    const int* __restrict__ seqs_data, const int* __restrict__ tmat,
    const float* __restrict__ tKtab, const float* __restrict__ tVtab,
    float* __restrict__ x2)
{
    const int row = blockIdx.x;            // b*L + l
    const int l = row & (SEQL - 1);
    const int b = row >> 8;
    const int tid = threadIdx.x;
    const int m = tid;

    __shared__ float qrow[HDIM];
    __shared__ int   idxs[SEQL];
    __shared__ float As[NHEAD][SEQL];
    __shared__ float red[8];
    __shared__ float outred[4][HDIM];

    if (tid < HDIM) qrow[tid] = Qo[(size_t)row * HDIM + tid];
    int idx = tmat[(size_t)row * SEQL + m];
    idxs[m] = idx;
    const bool qpad = (seqs_data[row] == PADID);   // query-side padding mask!
    __syncthreads();

    const float4* kp4 = (const float4*)(Kp + (size_t)(b * SEQL + m) * HDIM);
    const float4* tk4 = (const float4*)(tKtab + (size_t)idx * HDIM);
    float s0 = 0.f, s1 = 0.f;
#pragma unroll
    for (int j = 0; j < 8; ++j) {
        float4 kv = kp4[j], tv = tk4[j];
        s0 += qrow[4*j+0]*(kv.x+tv.x) + qrow[4*j+1]*(kv.y+tv.y)
            + qrow[4*j+2]*(kv.z+tv.z) + qrow[4*j+3]*(kv.w+tv.w);
    }
#pragma unroll
    for (int j = 8; j < 16; ++j) {
        float4 kv = kp4[j], tv = tk4[j];
        s1 += qrow[4*j+0]*(kv.x+tv.x) + qrow[4*j+1]*(kv.y+tv.y)
            + qrow[4*j+2]*(kv.z+tv.z) + qrow[4*j+3]*(kv.w+tv.w);
    }
    const bool masked = (m > l) || qpad;
    s0 = masked ? NEGV : s0 * INV_SQRT_HS;
    s1 = masked ? NEGV : s1 * INV_SQRT_HS;

    const int lane = tid & 63, wv = tid >> 6;
    // block max
    float a0 = s0, a1 = s1;
#pragma unroll
    for (int o = 32; o > 0; o >>= 1) {
        a0 = fmaxf(a0, __shfl_xor(a0, o));
        a1 = fmaxf(a1, __shfl_xor(a1, o));
    }
    if (lane == 0) { red[wv] = a0; red[4 + wv] = a1; }
    __syncthreads();
    float m0 = fmaxf(fmaxf(red[0], red[1]), fmaxf(red[2], red[3]));
    float m1 = fmaxf(fmaxf(red[4], red[5]), fmaxf(red[6], red[7]));
    __syncthreads();
    // exp + block sum
    float p0 = __expf(s0 - m0), p1 = __expf(s1 - m1);
    float t0 = waveReduceSum(p0), t1 = waveReduceSum(p1);
    if (lane == 0) { red[wv] = t0; red[4 + wv] = t1; }
    __syncthreads();
    float sum0 = red[0] + red[1] + red[2] + red[3];
    float sum1 = red[4] + red[5] + red[6] + red[7];
    As[0][m] = p0 / sum0;
    As[1][m] = p1 / sum1;
    __syncthreads();

    // Output: thread -> (chunk, hd); A[h][mm] and idxs[mm] broadcast from LDS.
    const int hd = tid & 63;
    const int chunk = tid >> 6;
    const int h = hd >> 5;
    const float* vbase = Vp + (size_t)(b * SEQL) * HDIM + hd;
    float acc = 0.f;
    const int mend = qpad ? SEQL : (l + 1);
    const int mlo = chunk * 64;
    const int mhi = min(mlo + 64, mend);
    for (int mm = mlo; mm < mhi; ++mm) {
        acc += As[h][mm] * (vbase[(size_t)mm * HDIM]
                            + tVtab[(size_t)idxs[mm] * HDIM + hd]);
    }
    outred[chunk][hd] = acc;
    __syncthreads();
    if (tid < HDIM) {
        float o = outred[0][tid] + outred[1][tid] + outred[2][tid] + outred[3][tid];
        x2[(size_t)row * HDIM + tid] = q_in[(size_t)row * HDIM + tid] + o;
    }
}

// One wave per row: LN2 + FFN (relu GEMV x2) + residual + keep-mask.
__global__ __launch_bounds__(64) void ffn_kernel(
    const float* __restrict__ x2, const int* __restrict__ seqs_data,
    const float* __restrict__ g2, const float* __restrict__ bg2,
    const float* __restrict__ W1, const float* __restrict__ bb1,
    const float* __restrict__ W2, const float* __restrict__ bb2,
    float* __restrict__ xout)
{
    const int row = blockIdx.x;
    const int t = threadIdx.x;
    float x = x2[(size_t)row * HDIM + t];
    float mean = waveReduceSum(x) * (1.f / HDIM);
    float d = x - mean;
    float var = waveReduceSum(d * d) * (1.f / HDIM);
    float s = g2[t] * d / sqrtf(var + LNEPS) + bg2[t];

    __shared__ float ss[HDIM];
    __shared__ float hs[HDIM];
    ss[t] = s;
    __syncthreads();
    const float4* w14 = (const float4*)(W1 + (size_t)t * HDIM);
    float acc = 0.f;
#pragma unroll
    for (int j = 0; j < 16; ++j) {
        float4 w = w14[j];
        acc += ss[4*j]*w.x + ss[4*j+1]*w.y + ss[4*j+2]*w.z + ss[4*j+3]*w.w;
    }
    float h = fmaxf(acc + bb1[t], 0.f);
    hs[t] = h;
    __syncthreads();
    const float4* w24 = (const float4*)(W2 + (size_t)t * HDIM);
    float acc2 = 0.f;
#pragma unroll
    for (int j = 0; j < 16; ++j) {
        float4 w = w24[j];
        acc2 += hs[4*j]*w.x + hs[4*j+1]*w.y + hs[4*j+2]*w.z + hs[4*j+3]*w.w;
    }
    float y = acc2 + bb2[t] + s;
    if (seqs_data[row] == PADID) y = 0.f;
    xout[(size_t)row * HDIM + t] = y;
}

__global__ __launch_bounds__(64) void final_ln_kernel(
    const float* __restrict__ xin,
    const float* __restrict__ g, const float* __restrict__ bb,
    float* __restrict__ out)
{
    const int row = blockIdx.x;
    const int t = threadIdx.x;
    float x = xin[(size_t)row * HDIM + t];
    float mean = waveReduceSum(x) * (1.f / HDIM);
    float d = x - mean;
    float var = waveReduceSum(d * d) * (1.f / HDIM);
    out[(size_t)row * HDIM + t] = g[t] * d / sqrtf(var + LNEPS) + bb[t];
}

extern "C" void kernel_launch(void* const* d_in, const int* in_sizes, int n_in,
                              void* d_out, int out_size, void* d_ws, size_t ws_size,
                              hipStream_t stream) {
    const int*   seqs_data = (const int*)d_in[0];
    const float* seqs      = (const float*)d_in[1];
    const int*   positions = (const int*)d_in[2];
    const int*   tmat      = (const int*)d_in[3];
    const float* apK       = (const float*)d_in[4];
    const float* apV       = (const float*)d_in[5];
    const float* tKtab     = (const float*)d_in[6];
    const float* tVtab     = (const float*)d_in[7];
    const float* Qw = (const float*)d_in[8];
    const float* Qb = (const float*)d_in[9];
    const float* Kw = (const float*)d_in[10];
    const float* Kb = (const float*)d_in[11];
    const float* Vw = (const float*)d_in[12];
    const float* Vb = (const float*)d_in[13];
    const float* g1 = (const float*)d_in[14];
    const float* b1 = (const float*)d_in[15];
    const float* g2 = (const float*)d_in[16];
    const float* b2 = (const float*)d_in[17];
    const float* W1 = (const float*)d_in[18];
    const float* fb1 = (const float*)d_in[19];
    const float* W2 = (const float*)d_in[20];
    const float* fb2 = (const float*)d_in[21];
    const float* lastg = (const float*)d_in[22];
    const float* lastb = (const float*)d_in[23];

    const int N = BATCH * SEQL * HDIM;   // 262144
    float* ws   = (float*)d_ws;
    float* x    = ws;          // layer activations (also used as x2 target)
    float* q_in = ws + 1 * (size_t)N;
    float* Qo   = ws + 2 * (size_t)N;
    float* Kp   = ws + 3 * (size_t)N;
    float* Vp   = ws + 4 * (size_t)N;

    const int rows = BATCH * SEQL;       // 4096

    for (int i = 0; i < NBLK; ++i) {
        const float* xin = (i == 0) ? seqs : x;
        prep_proj_kernel<<<rows, 64, 0, stream>>>(
            xin, seqs_data, positions,
            Qw + (size_t)i * HDIM * HDIM, Qb + (size_t)i * HDIM,
            Kw + (size_t)i * HDIM * HDIM, Kb + (size_t)i * HDIM,
            Vw + (size_t)i * HDIM * HDIM, Vb + (size_t)i * HDIM,
            g1 + (size_t)i * HDIM, b1 + (size_t)i * HDIM,
            apK, apV, q_in, Qo, Kp, Vp, (i == 0) ? 1 : 0);
        attn_kernel<<<rows, 256, 0, stream>>>(
            Qo, Kp, Vp, q_in, seqs_data, tmat, tKtab, tVtab, x);
        ffn_kernel<<<rows, 64, 0, stream>>>(
            x, seqs_data, g2 + (size_t)i * HDIM, b2 + (size_t)i * HDIM,
            W1 + (size_t)i * HDIM * HDIM, fb1 + (size_t)i * HDIM,
            W2 + (size_t)i * HDIM * HDIM, fb2 + (size_t)i * HDIM, x);
    }
    final_ln_kernel<<<rows, 64, 0, stream>>>(x, lastg, lastb, (float*)d_out);
}